// Round 7
// baseline (271.461 us; speedup 1.0000x reference)
//
#include <hip/hip_runtime.h>
#include <cstdint>
#include <cstddef>

#define NNODES 50000
#define NEDGES 800000
#define INDIM  256
#define HD     128   // H*D
#define NH     4
#define NEG    0.2f

#define BCAP   48        // bucket capacity per node (max deg @ Poisson(16), 50K draws ~ 42)
#define OVFCAP 32768     // overflow list capacity (never hit in practice; correctness path)

#define CONVW_BLKS 64
// fusedB block partition (gemm 128x256 | bucket-scatter 8 edges/thread)
#define GEMM_BLKS  ((NNODES + 127) / 128)           // 391
#define SCAT_BLKS  ((NEDGES + 2047) / 2048)         // 391

typedef __attribute__((ext_vector_type(8))) short   short8;   // 8 bf16 (4 VGPRs)
typedef __attribute__((ext_vector_type(8))) ushort  ushort8;
typedef __attribute__((ext_vector_type(4))) float   floatx4;

// f32 -> bf16 (round-to-nearest-even), raw bits
__device__ __forceinline__ ushort f2bf(float f) {
    unsigned u = __float_as_uint(f);
    unsigned r = u + 0x7fffu + ((u >> 16) & 1u);
    return (ushort)(r >> 16);
}
__device__ __forceinline__ float bf2f(ushort u) {
    return __uint_as_float(((unsigned)u) << 16);
}

// LDS chunk swizzle: conflict-free staging writes + fragment reads
__device__ __forceinline__ int swz(int c) { return c ^ ((c >> 4) & 7); }

// ================= conv_w: W convert+transpose (LDS-tiled): Wt[n][k] bf16 =========
__global__ __launch_bounds__(256) void convw_kernel(
        const float* __restrict__ Wsrc, const float* __restrict__ Wdst,
        ushort* __restrict__ Wt) {
    __shared__ float t[32][33];
    const int wb = blockIdx.x;                    // 0..63
    const int tid = threadIdx.x;
    int kb = (wb & 7) * 32, nb = (wb >> 3) * 32;
    int tx = tid & 31, ty = tid >> 5;
    for (int i = ty; i < 32; i += 8) {
        int k = kb + i, n = nb + tx;
        float v = (n < HD) ? Wsrc[(size_t)k * HD + n] : Wdst[(size_t)k * HD + (n - HD)];
        t[i][tx] = v;
    }
    __syncthreads();
    for (int i = ty; i < 32; i += 8) {
        int n = nb + i, k = kb + tx;
        Wt[(size_t)n * INDIM + k] = f2bf(t[tx][i]);
    }
}

// ================= fusedB: MFMA GEMM (128x256, f32 A direct) | bucket scatter =======
// GEMM writes el (bf16, ws) and er (f32, directly into d_out's out_feat region --
// er[n] is read only by node n's own wave in node_fused before it overwrites the
// same bytes with out_feat[n]; identical layout -> safe).
// Scatter: ONE atomic pass builds per-node buckets directly (no hist/scan/rowptr):
//   pos = atomicAdd(cnt[dst]); bucket[dst*BCAP+pos] = {e, src}. pos >= BCAP spills
//   to a small overflow list (correctness path, ~never taken at Poisson(16) degrees).
__global__ __launch_bounds__(256, 2) void fusedB_kernel(
        const float* __restrict__ h, const ushort* __restrict__ Wt,
        const float* __restrict__ bsrc, const float* __restrict__ bdst,
        ushort* __restrict__ el_bf, float* __restrict__ er,
        const int* __restrict__ src, const int* __restrict__ dst,
        int* __restrict__ cnt_work, int2* __restrict__ bucket,
        int* __restrict__ ovf_cnt, int4* __restrict__ ovf) {
    __shared__ ushort As[512 * 8];    // 128 rows x 32 k bf16 (8 KB)
    __shared__ ushort Bs[1024 * 8];   // 256 cols x 32 k bf16 (16 KB)

    const int bid = blockIdx.x;
    const int tid = threadIdx.x;

    if (bid >= GEMM_BLKS) {
        // ---- bucket scatter: 8 edges/thread (stride-256, coalesced loads) ----
        int base = (bid - GEMM_BLKS) * 2048 + tid;
        int ss[8], dd[8], pos[8];
#pragma unroll
        for (int k = 0; k < 8; ++k) {
            int e = base + k * 256;
            if (e < NEDGES) { ss[k] = src[e]; dd[k] = dst[e]; } else dd[k] = -1;
        }
#pragma unroll
        for (int k = 0; k < 8; ++k) {
            if (dd[k] >= 0) pos[k] = atomicAdd(cnt_work + dd[k], 1);
        }
#pragma unroll
        for (int k = 0; k < 8; ++k) {
            if (dd[k] >= 0) {
                int e = base + k * 256;
                if (pos[k] < BCAP) {
                    bucket[(size_t)dd[k] * BCAP + pos[k]] = make_int2(e, ss[k]);
                } else {
                    int o = atomicAdd(ovf_cnt, 1);
                    if (o < OVFCAP) ovf[o] = make_int4(e, ss[k], dd[k], 0);
                }
            }
        }
        return;
    }

    const int wave = tid >> 6, lane = tid & 63;
    const int row0 = bid * 128;
    const int l15  = lane & 15, quad = lane >> 4;

    floatx4 acc[2][16];
#pragma unroll
    for (int i = 0; i < 2; ++i)
#pragma unroll
        for (int j = 0; j < 16; ++j) acc[i][j] = (floatx4){0.f, 0.f, 0.f, 0.f};

    for (int kk = 0; kk < INDIM; kk += 32) {
        // ---- A staging: 512 chunks of 8, f32 source + convert ----
#pragma unroll
        for (int it = 0; it < 2; ++it) {
            int idx = tid + it * 256;    // 0..511
            int r = idx >> 2;            // 0..127 (row)
            int kq = idx & 3;            // k-quad (8 elems)
            int c = (r >> 4) * 64 + kq * 16 + (r & 15);
            int grow = row0 + r;
            ushort8 aw = (ushort8){0,0,0,0,0,0,0,0};
            if (grow < NNODES) {
                const float* p = h + (size_t)grow * INDIM + kk + kq * 8;
                float4 v0 = *(const float4*)p;
                float4 v1 = *(const float4*)(p + 4);
                aw[0] = f2bf(v0.x); aw[1] = f2bf(v0.y); aw[2] = f2bf(v0.z); aw[3] = f2bf(v0.w);
                aw[4] = f2bf(v1.x); aw[5] = f2bf(v1.y); aw[6] = f2bf(v1.z); aw[7] = f2bf(v1.w);
            }
            *(ushort8*)(As + swz(c) * 8) = aw;
        }
        // ---- B staging: 1024 chunks of 8 (256 cols) ----
#pragma unroll
        for (int it = 0; it < 4; ++it) {
            int idx = tid + it * 256;    // 0..1023
            int r = idx >> 2;            // 0..255 (col)
            int kq = idx & 3;
            int c = (r >> 4) * 64 + kq * 16 + (r & 15);   // 0..1023
            ushort8 bw = *(const ushort8*)(Wt + (size_t)r * INDIM + kk + kq * 8);
            *(ushort8*)(Bs + swz(c) * 8) = bw;
        }
        __syncthreads();

        short8 af[2];
#pragma unroll
        for (int tm = 0; tm < 2; ++tm) {
            int c = (wave * 2 + tm) * 64 + quad * 16 + l15;
            af[tm] = *(const short8*)(As + swz(c) * 8);
        }
#pragma unroll
        for (int tn = 0; tn < 16; ++tn) {
            int c = tn * 64 + quad * 16 + l15;
            short8 bfr = *(const short8*)(Bs + swz(c) * 8);
            acc[0][tn] = __builtin_amdgcn_mfma_f32_16x16x32_bf16(af[0], bfr, acc[0][tn], 0, 0, 0);
            acc[1][tn] = __builtin_amdgcn_mfma_f32_16x16x32_bf16(af[1], bfr, acc[1][tn], 0, 0, 0);
        }
        __syncthreads();
    }

    // epilogue: C/D layout col=lane&15, row=quad*4+reg
#pragma unroll
    for (int tn = 0; tn < 8; ++tn) {
        int col = tn * 16 + l15;              // 0..127 -> el
        float bias = bsrc[col];
#pragma unroll
        for (int tm = 0; tm < 2; ++tm)
#pragma unroll
            for (int reg = 0; reg < 4; ++reg) {
                int row = row0 + wave * 32 + tm * 16 + quad * 4 + reg;
                if (row < NNODES)
                    el_bf[(size_t)row * HD + col] = f2bf(acc[tm][tn][reg] + bias);
            }
    }
#pragma unroll
    for (int tn = 8; tn < 16; ++tn) {
        int col = tn * 16 + l15 - HD;         // 0..127 -> er
        float bias = bdst[col];
#pragma unroll
        for (int tm = 0; tm < 2; ++tm)
#pragma unroll
            for (int reg = 0; reg < 4; ++reg) {
                int row = row0 + wave * 32 + tm * 16 + quad * 4 + reg;
                if (row < NNODES)
                    er[(size_t)row * HD + col] = acc[tm][tn][reg] + bias;
            }
    }
}

// ================= node_fused: round-1 proven body + defer-max, bucket inputs =======
// one wave per node; lane l owns dims 2l,2l+1; head hh = l>>4.
// Structure UNCHANGED from the proven 71us shape (two batched rewrites regressed
// ~45%; the compiler's incremental vmcnt pipelining of this exact shape is
// load-bearing). Only the index source changed: bucket[n*BCAP+j] replaces
// epair[rowptr[n]+j]; cnt[n] replaces rowptr deltas. erout aliases out_feat
// (er[n] read before out_feat[n] write, same wave, same address). deg>BCAP
// contributions come from the overflow list (serial scan; ~never taken).
__global__ __launch_bounds__(256) void node_fused_kernel(
        const ushort* __restrict__ el_bf, float* __restrict__ erout,
        const int* __restrict__ cnt, const int2* __restrict__ bucket,
        const int* __restrict__ ovf_cnt, const int4* __restrict__ ovf,
        const float* __restrict__ attn, float* __restrict__ out_a) {
    __shared__ float sp[4][BCAP * NH];   // 768 B per wave

    const int wv = threadIdx.x >> 6;
    const int n = blockIdx.x * 4 + wv;
    if (n >= NNODES) return;
    const int lane = threadIdx.x & 63;
    const int hh = lane >> 4;
    const int degf = cnt[n];
    const int deg = (degf < BCAP) ? degf : BCAP;
    const int2* bkt = bucket + (size_t)n * BCAP;
    float* spw = sp[wv];
    const int l2 = lane * 2;

    const float2 rv = *(const float2*)(erout + (size_t)n * HD + l2);
    const float a0 = attn[l2], a1 = attn[l2 + 1];

    float m = -3.4e38f, lsum = 0.0f, acc0 = 0.0f, acc1 = 0.0f;

    if (deg > 0) {
        // preload first chunk of up to 16 edge-source indices (coalesced, clamped)
        int jj0 = (lane & 15);
        if (jj0 >= deg) jj0 = deg - 1;
        int si = bkt[jj0].y;

        for (int base = 0; base < deg; base += 16) {
            // issue all gathers of this chunk (wave-uniform scalar base per edge)
            ushort2 u[16];
#pragma unroll
            for (int j = 0; j < 16; ++j) {
                if (base + j < deg) {
                    int s = __builtin_amdgcn_readlane(si, j);
                    u[j] = *(const ushort2*)(el_bf + (size_t)s * HD + l2);
                }
            }
            // prefetch next chunk's indices (hides index-load latency under compute)
            int si_nxt = si;
            if (base + 16 < deg) {
                int jj = base + 16 + (lane & 15);
                if (jj >= deg) jj = deg - 1;
                si_nxt = bkt[jj].y;
            }
            // process chunk: per-edge, exec-masked tail (round-1 proven shape)
#pragma unroll
            for (int j = 0; j < 16; ++j) {
                if (base + j < deg) {
                    float evx = bf2f(u[j].x), evy = bf2f(u[j].y);
                    float x0 = evx + rv.x; x0 = fmaxf(x0, NEG * x0);
                    float x1 = evy + rv.y; x1 = fmaxf(x1, NEG * x1);
                    float p = x0 * a0 + x1 * a1;
                    p += __shfl_xor(p, 1, 16);
                    p += __shfl_xor(p, 2, 16);
                    p += __shfl_xor(p, 4, 16);
                    p += __shfl_xor(p, 8, 16);
                    if ((lane & 15) == 0) spw[(base + j) * NH + hh] = p;
                    // defer-max online softmax (group-uniform branch)
                    if (p > m) {
                        float sc = __expf(m - p);      // w = exp(p-p) = 1
                        lsum = fmaf(lsum, sc, 1.0f);
                        acc0 = fmaf(acc0, sc, evx);
                        acc1 = fmaf(acc1, sc, evy);
                        m = p;
                    } else {
                        float w = __expf(p - m);
                        lsum += w;
                        acc0 = fmaf(w, evx, acc0);
                        acc1 = fmaf(w, evy, acc1);
                    }
                }
            }
            si = si_nxt;
        }
    }

    // overflow contributions (deg > BCAP; correctness path, ~never taken)
    if (degf > BCAP) {
        int nov = *ovf_cnt; if (nov > OVFCAP) nov = OVFCAP;
        for (int i = 0; i < nov; ++i) {
            int4 t = ovf[i];
            if (t.z != n) continue;
            ushort2 uu = *(const ushort2*)(el_bf + (size_t)t.y * HD + l2);
            float evx = bf2f(uu.x), evy = bf2f(uu.y);
            float x0 = evx + rv.x; x0 = fmaxf(x0, NEG * x0);
            float x1 = evy + rv.y; x1 = fmaxf(x1, NEG * x1);
            float p = x0 * a0 + x1 * a1;
            p += __shfl_xor(p, 1, 16);
            p += __shfl_xor(p, 2, 16);
            p += __shfl_xor(p, 4, 16);
            p += __shfl_xor(p, 8, 16);
            if (p > m) {
                float sc = __expf(m - p);
                lsum = fmaf(lsum, sc, 1.0f);
                acc0 = fmaf(acc0, sc, evx);
                acc1 = fmaf(acc1, sc, evy);
                m = p;
            } else {
                float w = __expf(p - m);
                lsum += w;
                acc0 = fmaf(w, evx, acc0);
                acc1 = fmaf(w, evy, acc1);
            }
        }
    }

    // write aggregated features (overwrites er[n] -- same bytes, own wave)
    float2 o;
    if (degf == 0) { o.x = 0.0f; o.y = 0.0f; }
    else { float inv = 1.0f / lsum; o.x = acc0 * inv; o.y = acc1 * inv; }
    *(float2*)(erout + (size_t)n * HD + l2) = o;

    if (degf == 0) return;

    // normalize + write attention weights
    float inv = 1.0f / lsum;
    // broadcast (m, inv) of head (lane&3) from its group (values uniform in group)
    float mh   = __shfl(m,   (lane & 3) << 4, 64);
    float invh = __shfl(inv, (lane & 3) << 4, 64);
    for (int q = (lane >> 2); q < deg; q += 16) {
        int e = bkt[q].x;
        float p = spw[q * NH + (lane & 3)];
        out_a[(size_t)e * NH + (lane & 3)] = __expf(p - mh) * invh;
    }
    if (degf > BCAP) {
        int nov = *ovf_cnt; if (nov > OVFCAP) nov = OVFCAP;
        for (int i = 0; i < nov; ++i) {
            int4 t = ovf[i];
            if (t.z != n) continue;
            ushort2 uu = *(const ushort2*)(el_bf + (size_t)t.y * HD + l2);
            float evx = bf2f(uu.x), evy = bf2f(uu.y);
            float x0 = evx + rv.x; x0 = fmaxf(x0, NEG * x0);
            float x1 = evy + rv.y; x1 = fmaxf(x1, NEG * x1);
            float p = x0 * a0 + x1 * a1;
            p += __shfl_xor(p, 1, 16);
            p += __shfl_xor(p, 2, 16);
            p += __shfl_xor(p, 4, 16);
            p += __shfl_xor(p, 8, 16);
            if ((lane & 15) == 0)
                out_a[(size_t)t.x * NH + hh] = __expf(p - m) * inv;
        }
    }
}

extern "C" void kernel_launch(void* const* d_in, const int* in_sizes, int n_in,
                              void* d_out, int out_size, void* d_ws, size_t ws_size,
                              hipStream_t stream) {
    const float* h    = (const float*)d_in[0];
    const int*   src  = (const int*)d_in[1];
    const int*   dst  = (const int*)d_in[2];
    const float* Wsrc = (const float*)d_in[3];
    const float* bsrc = (const float*)d_in[4];
    const float* Wdst = (const float*)d_in[5];
    const float* bdst = (const float*)d_in[6];
    const float* attn = (const float*)d_in[7];

    float* out_feat = (float*)d_out;                       // N*128 (er lives here too)
    float* out_a    = out_feat + (size_t)NNODES * HD;      // E*4

    // workspace layout (16B-aligned chunks), ~33 MB total
    ushort* Wt       = (ushort*)d_ws;                        // 256*256 bf16 (128 KB)
    ushort* el_bf    = Wt + 2 * HD * INDIM;                  // N*128 bf16 (12.8 MB)
    int*    cnt_work = (int*)(el_bf + (size_t)NNODES * HD);  // N (200 KB)
    int*    ovf_cnt  = cnt_work + NNODES;                    // 1 (+pad)
    int4*   ovf      = (int4*)(ovf_cnt + 4);                 // OVFCAP*16B (512 KB)
    int2*   bucket   = (int2*)(ovf + OVFCAP);                // N*BCAP*8B (19.2 MB)

    hipMemsetAsync(cnt_work, 0, (NNODES + 4) * sizeof(int), stream);

    // conv_w: W convert+transpose (producer for GEMM)
    convw_kernel<<<CONVW_BLKS, 256, 0, stream>>>(Wsrc, Wdst, Wt);

    // fusedB: MFMA GEMM 128x256 (el -> ws, er -> d_out) | single-pass bucket scatter
    fusedB_kernel<<<GEMM_BLKS + SCAT_BLKS, 256, 0, stream>>>(
        h, Wt, bsrc, bdst, el_bf, out_feat, src, dst, cnt_work, bucket, ovf_cnt, ovf);

    node_fused_kernel<<<(NNODES + 3) / 4, 256, 0, stream>>>(
        el_bf, out_feat, cnt_work, bucket, ovf_cnt, ovf, attn, out_a);
}

// Round 8
// 270.516 us; speedup vs baseline: 1.0035x; 1.0035x over previous
//
#include <hip/hip_runtime.h>
#include <cstdint>
#include <cstddef>

#define NNODES 50000
#define NEDGES 800000
#define INDIM  256
#define HD     128   // H*D
#define NH     4
#define NEG    0.2f

#define BCAP   48        // bucket capacity per node (max deg @ Poisson(16), 50K draws ~ 42)
#define OVFCAP 32768     // overflow list capacity (never hit in practice; correctness path)

#define CONVW_BLKS 64
// fusedB block partition (gemm 128x256 | bucket-scatter 8 edges/thread)
#define GEMM_BLKS  ((NNODES + 127) / 128)           // 391
#define SCAT_BLKS  ((NEDGES + 2047) / 2048)         // 391

typedef __attribute__((ext_vector_type(8))) short   short8;   // 8 bf16 (4 VGPRs)
typedef __attribute__((ext_vector_type(8))) ushort  ushort8;
typedef __attribute__((ext_vector_type(4))) float   floatx4;

// f32 -> bf16 (round-to-nearest-even), raw bits
__device__ __forceinline__ ushort f2bf(float f) {
    unsigned u = __float_as_uint(f);
    unsigned r = u + 0x7fffu + ((u >> 16) & 1u);
    return (ushort)(r >> 16);
}
__device__ __forceinline__ float bf2f(ushort u) {
    return __uint_as_float(((unsigned)u) << 16);
}

// LDS chunk swizzle: conflict-free staging writes + fragment reads
__device__ __forceinline__ int swz(int c) { return c ^ ((c >> 4) & 7); }

// ================= conv_w: W convert+transpose (LDS-tiled): Wt[n][k] bf16 =========
__global__ __launch_bounds__(256) void convw_kernel(
        const float* __restrict__ Wsrc, const float* __restrict__ Wdst,
        ushort* __restrict__ Wt) {
    __shared__ float t[32][33];
    const int wb = blockIdx.x;                    // 0..63
    const int tid = threadIdx.x;
    int kb = (wb & 7) * 32, nb = (wb >> 3) * 32;
    int tx = tid & 31, ty = tid >> 5;
    for (int i = ty; i < 32; i += 8) {
        int k = kb + i, n = nb + tx;
        float v = (n < HD) ? Wsrc[(size_t)k * HD + n] : Wdst[(size_t)k * HD + (n - HD)];
        t[i][tx] = v;
    }
    __syncthreads();
    for (int i = ty; i < 32; i += 8) {
        int n = nb + i, k = kb + tx;
        Wt[(size_t)n * INDIM + k] = f2bf(t[tx][i]);
    }
}

// ================= fusedB: MFMA GEMM (128x256, f32 A direct) | bucket scatter =======
// GEMM writes el (bf16, ws) and er (f32, directly into d_out's out_feat region --
// er[n] is read only by node n's own wave in node_fused before it overwrites the
// same bytes with out_feat[n]; identical layout -> safe).
// Scatter: ONE atomic pass builds per-node buckets directly (no hist/scan/rowptr):
//   pos = atomicAdd(cnt[dst]); bucket[dst*BCAP+pos] = {e, src}. pos >= BCAP spills
//   to a small overflow list (correctness path, ~never taken at Poisson(16) degrees).
__global__ __launch_bounds__(256, 2) void fusedB_kernel(
        const float* __restrict__ h, const ushort* __restrict__ Wt,
        const float* __restrict__ bsrc, const float* __restrict__ bdst,
        ushort* __restrict__ el_bf, float* __restrict__ er,
        const int* __restrict__ src, const int* __restrict__ dst,
        int* __restrict__ cnt_work, int2* __restrict__ bucket,
        int* __restrict__ ovf_cnt, int4* __restrict__ ovf) {
    __shared__ ushort As[512 * 8];    // 128 rows x 32 k bf16 (8 KB)
    __shared__ ushort Bs[1024 * 8];   // 256 cols x 32 k bf16 (16 KB)

    const int bid = blockIdx.x;
    const int tid = threadIdx.x;

    if (bid >= GEMM_BLKS) {
        // ---- bucket scatter: 8 edges/thread (stride-256, coalesced loads) ----
        int base = (bid - GEMM_BLKS) * 2048 + tid;
        int ss[8], dd[8], pos[8];
#pragma unroll
        for (int k = 0; k < 8; ++k) {
            int e = base + k * 256;
            if (e < NEDGES) { ss[k] = src[e]; dd[k] = dst[e]; } else dd[k] = -1;
        }
#pragma unroll
        for (int k = 0; k < 8; ++k) {
            if (dd[k] >= 0) pos[k] = atomicAdd(cnt_work + dd[k], 1);
        }
#pragma unroll
        for (int k = 0; k < 8; ++k) {
            if (dd[k] >= 0) {
                int e = base + k * 256;
                if (pos[k] < BCAP) {
                    bucket[(size_t)dd[k] * BCAP + pos[k]] = make_int2(e, ss[k]);
                } else {
                    int o = atomicAdd(ovf_cnt, 1);
                    if (o < OVFCAP) ovf[o] = make_int4(e, ss[k], dd[k], 0);
                }
            }
        }
        return;
    }

    const int wave = tid >> 6, lane = tid & 63;
    const int row0 = bid * 128;
    const int l15  = lane & 15, quad = lane >> 4;

    floatx4 acc[2][16];
#pragma unroll
    for (int i = 0; i < 2; ++i)
#pragma unroll
        for (int j = 0; j < 16; ++j) acc[i][j] = (floatx4){0.f, 0.f, 0.f, 0.f};

    for (int kk = 0; kk < INDIM; kk += 32) {
        // ---- A staging: 512 chunks of 8, f32 source + convert ----
#pragma unroll
        for (int it = 0; it < 2; ++it) {
            int idx = tid + it * 256;    // 0..511
            int r = idx >> 2;            // 0..127 (row)
            int kq = idx & 3;            // k-quad (8 elems)
            int c = (r >> 4) * 64 + kq * 16 + (r & 15);
            int grow = row0 + r;
            ushort8 aw = (ushort8){0,0,0,0,0,0,0,0};
            if (grow < NNODES) {
                const float* p = h + (size_t)grow * INDIM + kk + kq * 8;
                float4 v0 = *(const float4*)p;
                float4 v1 = *(const float4*)(p + 4);
                aw[0] = f2bf(v0.x); aw[1] = f2bf(v0.y); aw[2] = f2bf(v0.z); aw[3] = f2bf(v0.w);
                aw[4] = f2bf(v1.x); aw[5] = f2bf(v1.y); aw[6] = f2bf(v1.z); aw[7] = f2bf(v1.w);
            }
            *(ushort8*)(As + swz(c) * 8) = aw;
        }
        // ---- B staging: 1024 chunks of 8 (256 cols) ----
#pragma unroll
        for (int it = 0; it < 4; ++it) {
            int idx = tid + it * 256;    // 0..1023
            int r = idx >> 2;            // 0..255 (col)
            int kq = idx & 3;
            int c = (r >> 4) * 64 + kq * 16 + (r & 15);   // 0..1023
            ushort8 bw = *(const ushort8*)(Wt + (size_t)r * INDIM + kk + kq * 8);
            *(ushort8*)(Bs + swz(c) * 8) = bw;
        }
        __syncthreads();

        short8 af[2];
#pragma unroll
        for (int tm = 0; tm < 2; ++tm) {
            int c = (wave * 2 + tm) * 64 + quad * 16 + l15;
            af[tm] = *(const short8*)(As + swz(c) * 8);
        }
#pragma unroll
        for (int tn = 0; tn < 16; ++tn) {
            int c = tn * 64 + quad * 16 + l15;
            short8 bfr = *(const short8*)(Bs + swz(c) * 8);
            acc[0][tn] = __builtin_amdgcn_mfma_f32_16x16x32_bf16(af[0], bfr, acc[0][tn], 0, 0, 0);
            acc[1][tn] = __builtin_amdgcn_mfma_f32_16x16x32_bf16(af[1], bfr, acc[1][tn], 0, 0, 0);
        }
        __syncthreads();
    }

    // epilogue: C/D layout col=lane&15, row=quad*4+reg
#pragma unroll
    for (int tn = 0; tn < 8; ++tn) {
        int col = tn * 16 + l15;              // 0..127 -> el
        float bias = bsrc[col];
#pragma unroll
        for (int tm = 0; tm < 2; ++tm)
#pragma unroll
            for (int reg = 0; reg < 4; ++reg) {
                int row = row0 + wave * 32 + tm * 16 + quad * 4 + reg;
                if (row < NNODES)
                    el_bf[(size_t)row * HD + col] = f2bf(acc[tm][tn][reg] + bias);
            }
    }
#pragma unroll
    for (int tn = 8; tn < 16; ++tn) {
        int col = tn * 16 + l15 - HD;         // 0..127 -> er
        float bias = bdst[col];
#pragma unroll
        for (int tm = 0; tm < 2; ++tm)
#pragma unroll
            for (int reg = 0; reg < 4; ++reg) {
                int row = row0 + wave * 32 + tm * 16 + quad * 4 + reg;
                if (row < NNODES)
                    er[(size_t)row * HD + col] = acc[tm][tn][reg] + bias;
            }
    }
}

// ================= node_fused: round-1 proven BRANCHLESS body, bucket inputs =======
// one wave per node; lane l owns dims 2l,2l+1; head hh = l>>4.
// Inner update is the branchless online-softmax (round-1 71us form). Defer-max was
// REVERTED: its (p>m) branch is uniform per 16-lane head-group but NOT per 64-lane
// exec mask -- the 4 groups disagree on ~55% of edges, so the wave ran BOTH paths
// exec-masked (+28% VALU cycles measured, 73->102us). Do not reintroduce branches
// in this loop. Index source: bucket[n*BCAP+j], deg from cnt[n]; erout aliases
// out_feat (er[n] read before out_feat[n] write, same wave, same address).
// deg>BCAP spills handled via overflow list (serial scan; ~never taken).
__global__ __launch_bounds__(256) void node_fused_kernel(
        const ushort* __restrict__ el_bf, float* __restrict__ erout,
        const int* __restrict__ cnt, const int2* __restrict__ bucket,
        const int* __restrict__ ovf_cnt, const int4* __restrict__ ovf,
        const float* __restrict__ attn, float* __restrict__ out_a) {
    __shared__ float sp[4][BCAP * NH];   // 768 B per wave

    const int wv = threadIdx.x >> 6;
    const int n = blockIdx.x * 4 + wv;
    if (n >= NNODES) return;
    const int lane = threadIdx.x & 63;
    const int hh = lane >> 4;
    const int degf = cnt[n];
    const int deg = (degf < BCAP) ? degf : BCAP;
    const int2* bkt = bucket + (size_t)n * BCAP;
    float* spw = sp[wv];
    const int l2 = lane * 2;

    const float2 rv = *(const float2*)(erout + (size_t)n * HD + l2);
    const float a0 = attn[l2], a1 = attn[l2 + 1];

    float m = -3.4e38f, lsum = 0.0f, acc0 = 0.0f, acc1 = 0.0f;

    if (deg > 0) {
        // preload first chunk of up to 16 edge-source indices (coalesced, clamped)
        int jj0 = (lane & 15);
        if (jj0 >= deg) jj0 = deg - 1;
        int si = bkt[jj0].y;

        for (int base = 0; base < deg; base += 16) {
            // issue all gathers of this chunk (wave-uniform scalar base per edge)
            ushort2 u[16];
#pragma unroll
            for (int j = 0; j < 16; ++j) {
                if (base + j < deg) {
                    int s = __builtin_amdgcn_readlane(si, j);
                    u[j] = *(const ushort2*)(el_bf + (size_t)s * HD + l2);
                }
            }
            // prefetch next chunk's indices (hides index-load latency under compute)
            int si_nxt = si;
            if (base + 16 < deg) {
                int jj = base + 16 + (lane & 15);
                if (jj >= deg) jj = deg - 1;
                si_nxt = bkt[jj].y;
            }
            // process chunk: per-edge, branchless online softmax (round-1 proven shape)
#pragma unroll
            for (int j = 0; j < 16; ++j) {
                if (base + j < deg) {
                    float evx = bf2f(u[j].x), evy = bf2f(u[j].y);
                    float x0 = evx + rv.x; x0 = fmaxf(x0, NEG * x0);
                    float x1 = evy + rv.y; x1 = fmaxf(x1, NEG * x1);
                    float p = x0 * a0 + x1 * a1;
                    p += __shfl_xor(p, 1, 16);
                    p += __shfl_xor(p, 2, 16);
                    p += __shfl_xor(p, 4, 16);
                    p += __shfl_xor(p, 8, 16);
                    if ((lane & 15) == 0) spw[(base + j) * NH + hh] = p;
                    float mn = fmaxf(m, p);
                    float sc = __expf(m - mn);
                    float w  = __expf(p - mn);
                    lsum = lsum * sc + w;
                    acc0 = acc0 * sc + w * evx;
                    acc1 = acc1 * sc + w * evy;
                    m = mn;
                }
            }
            si = si_nxt;
        }
    }

    // overflow contributions (deg > BCAP; correctness path, ~never taken)
    if (degf > BCAP) {
        int nov = *ovf_cnt; if (nov > OVFCAP) nov = OVFCAP;
        for (int i = 0; i < nov; ++i) {
            int4 t = ovf[i];
            if (t.z != n) continue;
            ushort2 uu = *(const ushort2*)(el_bf + (size_t)t.y * HD + l2);
            float evx = bf2f(uu.x), evy = bf2f(uu.y);
            float x0 = evx + rv.x; x0 = fmaxf(x0, NEG * x0);
            float x1 = evy + rv.y; x1 = fmaxf(x1, NEG * x1);
            float p = x0 * a0 + x1 * a1;
            p += __shfl_xor(p, 1, 16);
            p += __shfl_xor(p, 2, 16);
            p += __shfl_xor(p, 4, 16);
            p += __shfl_xor(p, 8, 16);
            float mn = fmaxf(m, p);
            float sc = __expf(m - mn);
            float w  = __expf(p - mn);
            lsum = lsum * sc + w;
            acc0 = acc0 * sc + w * evx;
            acc1 = acc1 * sc + w * evy;
            m = mn;
        }
    }

    // write aggregated features (overwrites er[n] -- same bytes, own wave)
    float2 o;
    if (degf == 0) { o.x = 0.0f; o.y = 0.0f; }
    else { float inv = 1.0f / lsum; o.x = acc0 * inv; o.y = acc1 * inv; }
    *(float2*)(erout + (size_t)n * HD + l2) = o;

    if (degf == 0) return;

    // normalize + write attention weights
    float inv = 1.0f / lsum;
    // broadcast (m, inv) of head (lane&3) from its group (values uniform in group)
    float mh   = __shfl(m,   (lane & 3) << 4, 64);
    float invh = __shfl(inv, (lane & 3) << 4, 64);
    for (int q = (lane >> 2); q < deg; q += 16) {
        int e = bkt[q].x;
        float p = spw[q * NH + (lane & 3)];
        out_a[(size_t)e * NH + (lane & 3)] = __expf(p - mh) * invh;
    }
    if (degf > BCAP) {
        int nov = *ovf_cnt; if (nov > OVFCAP) nov = OVFCAP;
        for (int i = 0; i < nov; ++i) {
            int4 t = ovf[i];
            if (t.z != n) continue;
            ushort2 uu = *(const ushort2*)(el_bf + (size_t)t.y * HD + l2);
            float evx = bf2f(uu.x), evy = bf2f(uu.y);
            float x0 = evx + rv.x; x0 = fmaxf(x0, NEG * x0);
            float x1 = evy + rv.y; x1 = fmaxf(x1, NEG * x1);
            float p = x0 * a0 + x1 * a1;
            p += __shfl_xor(p, 1, 16);
            p += __shfl_xor(p, 2, 16);
            p += __shfl_xor(p, 4, 16);
            p += __shfl_xor(p, 8, 16);
            if ((lane & 15) == 0)
                out_a[(size_t)t.x * NH + hh] = __expf(p - m) * inv;
        }
    }
}

extern "C" void kernel_launch(void* const* d_in, const int* in_sizes, int n_in,
                              void* d_out, int out_size, void* d_ws, size_t ws_size,
                              hipStream_t stream) {
    const float* h    = (const float*)d_in[0];
    const int*   src  = (const int*)d_in[1];
    const int*   dst  = (const int*)d_in[2];
    const float* Wsrc = (const float*)d_in[3];
    const float* bsrc = (const float*)d_in[4];
    const float* Wdst = (const float*)d_in[5];
    const float* bdst = (const float*)d_in[6];
    const float* attn = (const float*)d_in[7];

    float* out_feat = (float*)d_out;                       // N*128 (er lives here too)
    float* out_a    = out_feat + (size_t)NNODES * HD;      // E*4

    // workspace layout (16B-aligned chunks), ~33 MB total
    ushort* Wt       = (ushort*)d_ws;                        // 256*256 bf16 (128 KB)
    ushort* el_bf    = Wt + 2 * HD * INDIM;                  // N*128 bf16 (12.8 MB)
    int*    cnt_work = (int*)(el_bf + (size_t)NNODES * HD);  // N (200 KB)
    int*    ovf_cnt  = cnt_work + NNODES;                    // 1 (+pad)
    int4*   ovf      = (int4*)(ovf_cnt + 4);                 // OVFCAP*16B (512 KB)
    int2*   bucket   = (int2*)(ovf + OVFCAP);                // N*BCAP*8B (19.2 MB)

    hipMemsetAsync(cnt_work, 0, (NNODES + 4) * sizeof(int), stream);

    // conv_w: W convert+transpose (producer for GEMM)
    convw_kernel<<<CONVW_BLKS, 256, 0, stream>>>(Wsrc, Wdst, Wt);

    // fusedB: MFMA GEMM 128x256 (el -> ws, er -> d_out) | single-pass bucket scatter
    fusedB_kernel<<<GEMM_BLKS + SCAT_BLKS, 256, 0, stream>>>(
        h, Wt, bsrc, bdst, el_bf, out_feat, src, dst, cnt_work, bucket, ovf_cnt, ovf);

    node_fused_kernel<<<(NNODES + 3) / 4, 256, 0, stream>>>(
        el_bf, out_feat, cnt_work, bucket, ovf_cnt, ovf, attn, out_a);
}

// Round 9
// 266.508 us; speedup vs baseline: 1.0186x; 1.0150x over previous
//
#include <hip/hip_runtime.h>
#include <cstdint>
#include <cstddef>

#define NNODES 50000
#define NEDGES 800000
#define INDIM  256
#define HD     128   // H*D
#define NH     4
#define NEG    0.2f

#define BCAP   32        // bucket capacity per node (12.8 MB region; deg>32 ~10 nodes -> ovf)
#define OVFCAP 32768     // overflow list capacity (expected use ~200-400 entries)

// fusedPre partition (clear cnt | conv_w)
#define CLR_BLKS   49                               // (NNODES+4)/4 int4s / 256
#define CONVW_BLKS 64
// fusedB block partition (gemm 128x256 | bucket-scatter 8 edges/thread)
#define GEMM_BLKS  ((NNODES + 127) / 128)           // 391
#define SCAT_BLKS  ((NEDGES + 2047) / 2048)         // 391

typedef __attribute__((ext_vector_type(8))) short   short8;   // 8 bf16 (4 VGPRs)
typedef __attribute__((ext_vector_type(8))) ushort  ushort8;
typedef __attribute__((ext_vector_type(4))) float   floatx4;

// f32 -> bf16 (round-to-nearest-even), raw bits
__device__ __forceinline__ ushort f2bf(float f) {
    unsigned u = __float_as_uint(f);
    unsigned r = u + 0x7fffu + ((u >> 16) & 1u);
    return (ushort)(r >> 16);
}
__device__ __forceinline__ float bf2f(ushort u) {
    return __uint_as_float(((unsigned)u) << 16);
}

// LDS chunk swizzle: conflict-free staging writes + fragment reads
__device__ __forceinline__ int swz(int c) { return c ^ ((c >> 4) & 7); }

// ================= fusedPre: clear cnt/ovf_cnt | W convert+transpose =================
__global__ __launch_bounds__(256) void fusedPre_kernel(
        int* __restrict__ cnt_work,
        const float* __restrict__ Wsrc, const float* __restrict__ Wdst,
        ushort* __restrict__ Wt) {
    __shared__ float t[32][33];
    const int bid = blockIdx.x;
    const int tid = threadIdx.x;

    if (bid < CLR_BLKS) {
        // clear cnt_work[NNODES] + ovf_cnt (+pad) with int4 stores
        int i = bid * 256 + tid;
        if (i < (NNODES + 4) / 4 + 1)
            ((int4*)cnt_work)[i] = make_int4(0, 0, 0, 0);
        return;
    }
    // ---- W convert+transpose (LDS-tiled): Wt[n][k] bf16 ----
    int wb = bid - CLR_BLKS;                      // 0..63
    int kb = (wb & 7) * 32, nb = (wb >> 3) * 32;
    int tx = tid & 31, ty = tid >> 5;
    for (int i = ty; i < 32; i += 8) {
        int k = kb + i, n = nb + tx;
        float v = (n < HD) ? Wsrc[(size_t)k * HD + n] : Wdst[(size_t)k * HD + (n - HD)];
        t[i][tx] = v;
    }
    __syncthreads();
    for (int i = ty; i < 32; i += 8) {
        int n = nb + i, k = kb + tx;
        Wt[(size_t)n * INDIM + k] = f2bf(t[tx][i]);
    }
}

// ================= fusedB: MFMA GEMM (128x256, f32 A direct) | bucket scatter =======
// GEMM writes el (bf16, ws) and er (f32, directly into d_out's out_feat region --
// er[n] is read only by node n's own wave in node_fused before it overwrites the
// same bytes with out_feat[n]; identical layout -> safe).
// Scatter: ONE atomic pass builds per-node buckets directly (no hist/scan/rowptr):
//   pos = atomicAdd(cnt[dst]); bucket[dst*BCAP+pos] = {e, src}. pos >= BCAP spills
//   to the overflow list (~10 nodes at Poisson(16) with BCAP=32).
__global__ __launch_bounds__(256, 2) void fusedB_kernel(
        const float* __restrict__ h, const ushort* __restrict__ Wt,
        const float* __restrict__ bsrc, const float* __restrict__ bdst,
        ushort* __restrict__ el_bf, float* __restrict__ er,
        const int* __restrict__ src, const int* __restrict__ dst,
        int* __restrict__ cnt_work, int2* __restrict__ bucket,
        int* __restrict__ ovf_cnt, int4* __restrict__ ovf) {
    __shared__ ushort As[512 * 8];    // 128 rows x 32 k bf16 (8 KB)
    __shared__ ushort Bs[1024 * 8];   // 256 cols x 32 k bf16 (16 KB)

    const int bid = blockIdx.x;
    const int tid = threadIdx.x;

    if (bid >= GEMM_BLKS) {
        // ---- bucket scatter: 8 edges/thread (stride-256, coalesced loads) ----
        int base = (bid - GEMM_BLKS) * 2048 + tid;
        int ss[8], dd[8], pos[8];
#pragma unroll
        for (int k = 0; k < 8; ++k) {
            int e = base + k * 256;
            if (e < NEDGES) { ss[k] = src[e]; dd[k] = dst[e]; } else dd[k] = -1;
        }
#pragma unroll
        for (int k = 0; k < 8; ++k) {
            if (dd[k] >= 0) pos[k] = atomicAdd(cnt_work + dd[k], 1);
        }
#pragma unroll
        for (int k = 0; k < 8; ++k) {
            if (dd[k] >= 0) {
                int e = base + k * 256;
                if (pos[k] < BCAP) {
                    bucket[(size_t)dd[k] * BCAP + pos[k]] = make_int2(e, ss[k]);
                } else {
                    int o = atomicAdd(ovf_cnt, 1);
                    if (o < OVFCAP) ovf[o] = make_int4(e, ss[k], dd[k], 0);
                }
            }
        }
        return;
    }

    const int wave = tid >> 6, lane = tid & 63;
    const int row0 = bid * 128;
    const int l15  = lane & 15, quad = lane >> 4;

    floatx4 acc[2][16];
#pragma unroll
    for (int i = 0; i < 2; ++i)
#pragma unroll
        for (int j = 0; j < 16; ++j) acc[i][j] = (floatx4){0.f, 0.f, 0.f, 0.f};

    for (int kk = 0; kk < INDIM; kk += 32) {
        // ---- A staging: 512 chunks of 8, f32 source + convert ----
#pragma unroll
        for (int it = 0; it < 2; ++it) {
            int idx = tid + it * 256;    // 0..511
            int r = idx >> 2;            // 0..127 (row)
            int kq = idx & 3;            // k-quad (8 elems)
            int c = (r >> 4) * 64 + kq * 16 + (r & 15);
            int grow = row0 + r;
            ushort8 aw = (ushort8){0,0,0,0,0,0,0,0};
            if (grow < NNODES) {
                const float* p = h + (size_t)grow * INDIM + kk + kq * 8;
                float4 v0 = *(const float4*)p;
                float4 v1 = *(const float4*)(p + 4);
                aw[0] = f2bf(v0.x); aw[1] = f2bf(v0.y); aw[2] = f2bf(v0.z); aw[3] = f2bf(v0.w);
                aw[4] = f2bf(v1.x); aw[5] = f2bf(v1.y); aw[6] = f2bf(v1.z); aw[7] = f2bf(v1.w);
            }
            *(ushort8*)(As + swz(c) * 8) = aw;
        }
        // ---- B staging: 1024 chunks of 8 (256 cols) ----
#pragma unroll
        for (int it = 0; it < 4; ++it) {
            int idx = tid + it * 256;    // 0..1023
            int r = idx >> 2;            // 0..255 (col)
            int kq = idx & 3;
            int c = (r >> 4) * 64 + kq * 16 + (r & 15);   // 0..1023
            ushort8 bw = *(const ushort8*)(Wt + (size_t)r * INDIM + kk + kq * 8);
            *(ushort8*)(Bs + swz(c) * 8) = bw;
        }
        __syncthreads();

        short8 af[2];
#pragma unroll
        for (int tm = 0; tm < 2; ++tm) {
            int c = (wave * 2 + tm) * 64 + quad * 16 + l15;
            af[tm] = *(const short8*)(As + swz(c) * 8);
        }
#pragma unroll
        for (int tn = 0; tn < 16; ++tn) {
            int c = tn * 64 + quad * 16 + l15;
            short8 bfr = *(const short8*)(Bs + swz(c) * 8);
            acc[0][tn] = __builtin_amdgcn_mfma_f32_16x16x32_bf16(af[0], bfr, acc[0][tn], 0, 0, 0);
            acc[1][tn] = __builtin_amdgcn_mfma_f32_16x16x32_bf16(af[1], bfr, acc[1][tn], 0, 0, 0);
        }
        __syncthreads();
    }

    // epilogue: C/D layout col=lane&15, row=quad*4+reg
#pragma unroll
    for (int tn = 0; tn < 8; ++tn) {
        int col = tn * 16 + l15;              // 0..127 -> el
        float bias = bsrc[col];
#pragma unroll
        for (int tm = 0; tm < 2; ++tm)
#pragma unroll
            for (int reg = 0; reg < 4; ++reg) {
                int row = row0 + wave * 32 + tm * 16 + quad * 4 + reg;
                if (row < NNODES)
                    el_bf[(size_t)row * HD + col] = f2bf(acc[tm][tn][reg] + bias);
            }
    }
#pragma unroll
    for (int tn = 8; tn < 16; ++tn) {
        int col = tn * 16 + l15 - HD;         // 0..127 -> er
        float bias = bdst[col];
#pragma unroll
        for (int tm = 0; tm < 2; ++tm)
#pragma unroll
            for (int reg = 0; reg < 4; ++reg) {
                int row = row0 + wave * 32 + tm * 16 + quad * 4 + reg;
                if (row < NNODES)
                    er[(size_t)row * HD + col] = acc[tm][tn][reg] + bias;
            }
    }
}

// ================= node_fused: branchless proven body, dependency-broken indices ====
// one wave per node; lane l owns dims 2l,2l+1; head hh = l>>4.
// KEY FIX vs r7/r8: index loads are UNCLAMPED (bucket rows are always BCAP slots;
// garbage beyond deg is loaded but never consumed -- readlane only for j<deg), so
// the index-row load no longer depends on cnt[n]: cnt and indices load in parallel,
// removing a ~900ns serial stage from every wave's startup chain (each wave owns
// ONE node, so the startup chain was a large fraction of its runtime). Bucket is
// 12.8 MB (BCAP=32) for better L2 residency of index rows. Inner loop body is the
// round-1 proven branchless shape -- do NOT restructure it.
__global__ __launch_bounds__(256) void node_fused_kernel(
        const ushort* __restrict__ el_bf, float* __restrict__ erout,
        const int* __restrict__ cnt, const int2* __restrict__ bucket,
        const int* __restrict__ ovf_cnt, const int4* __restrict__ ovf,
        const float* __restrict__ attn, float* __restrict__ out_a) {
    __shared__ float sp[4][BCAP * NH];   // 512 B per wave

    const int wv = threadIdx.x >> 6;
    const int n = blockIdx.x * 4 + wv;
    if (n >= NNODES) return;
    const int lane = threadIdx.x & 63;
    const int hh = lane >> 4;
    const int2* bkt = bucket + (size_t)n * BCAP;

    // issue index-row load FIRST (independent of cnt/er loads below)
    int si = bkt[lane & 15].y;           // unclamped: garbage beyond deg never consumed

    const int degf = cnt[n];
    const int deg = (degf < BCAP) ? degf : BCAP;
    float* spw = sp[wv];
    const int l2 = lane * 2;

    const float2 rv = *(const float2*)(erout + (size_t)n * HD + l2);
    const float a0 = attn[l2], a1 = attn[l2 + 1];

    float m = -3.4e38f, lsum = 0.0f, acc0 = 0.0f, acc1 = 0.0f;

    if (deg > 0) {
        for (int base = 0; base < deg; base += 16) {
            // issue all gathers of this chunk (wave-uniform scalar base per edge)
            ushort2 u[16];
#pragma unroll
            for (int j = 0; j < 16; ++j) {
                if (base + j < deg) {
                    int s = __builtin_amdgcn_readlane(si, j);
                    u[j] = *(const ushort2*)(el_bf + (size_t)s * HD + l2);
                }
            }
            // prefetch next chunk's indices (unclamped; base+16+15 <= BCAP-1 always)
            int si_nxt = si;
            if (base + 16 < deg) si_nxt = bkt[base + 16 + (lane & 15)].y;
            // process chunk: per-edge, branchless online softmax (round-1 proven shape)
#pragma unroll
            for (int j = 0; j < 16; ++j) {
                if (base + j < deg) {
                    float evx = bf2f(u[j].x), evy = bf2f(u[j].y);
                    float x0 = evx + rv.x; x0 = fmaxf(x0, NEG * x0);
                    float x1 = evy + rv.y; x1 = fmaxf(x1, NEG * x1);
                    float p = x0 * a0 + x1 * a1;
                    p += __shfl_xor(p, 1, 16);
                    p += __shfl_xor(p, 2, 16);
                    p += __shfl_xor(p, 4, 16);
                    p += __shfl_xor(p, 8, 16);
                    if ((lane & 15) == 0) spw[(base + j) * NH + hh] = p;
                    float mn = fmaxf(m, p);
                    float sc = __expf(m - mn);
                    float w  = __expf(p - mn);
                    lsum = lsum * sc + w;
                    acc0 = acc0 * sc + w * evx;
                    acc1 = acc1 * sc + w * evy;
                    m = mn;
                }
            }
            si = si_nxt;
        }
    }

    // overflow contributions (deg > BCAP; ~10 nodes at BCAP=32)
    if (degf > BCAP) {
        int nov = *ovf_cnt; if (nov > OVFCAP) nov = OVFCAP;
        for (int i = 0; i < nov; ++i) {
            int4 t = ovf[i];
            if (t.z != n) continue;
            ushort2 uu = *(const ushort2*)(el_bf + (size_t)t.y * HD + l2);
            float evx = bf2f(uu.x), evy = bf2f(uu.y);
            float x0 = evx + rv.x; x0 = fmaxf(x0, NEG * x0);
            float x1 = evy + rv.y; x1 = fmaxf(x1, NEG * x1);
            float p = x0 * a0 + x1 * a1;
            p += __shfl_xor(p, 1, 16);
            p += __shfl_xor(p, 2, 16);
            p += __shfl_xor(p, 4, 16);
            p += __shfl_xor(p, 8, 16);
            float mn = fmaxf(m, p);
            float sc = __expf(m - mn);
            float w  = __expf(p - mn);
            lsum = lsum * sc + w;
            acc0 = acc0 * sc + w * evx;
            acc1 = acc1 * sc + w * evy;
            m = mn;
        }
    }

    // write aggregated features (overwrites er[n] -- same bytes, own wave)
    float2 o;
    if (degf == 0) { o.x = 0.0f; o.y = 0.0f; }
    else { float inv = 1.0f / lsum; o.x = acc0 * inv; o.y = acc1 * inv; }
    *(float2*)(erout + (size_t)n * HD + l2) = o;

    if (degf == 0) return;

    // normalize + write attention weights
    float inv = 1.0f / lsum;
    // broadcast (m, inv) of head (lane&3) from its group (values uniform in group)
    float mh   = __shfl(m,   (lane & 3) << 4, 64);
    float invh = __shfl(inv, (lane & 3) << 4, 64);
    for (int q = (lane >> 2); q < deg; q += 16) {
        int e = bkt[q].x;
        float p = spw[q * NH + (lane & 3)];
        out_a[(size_t)e * NH + (lane & 3)] = __expf(p - mh) * invh;
    }
    if (degf > BCAP) {
        int nov = *ovf_cnt; if (nov > OVFCAP) nov = OVFCAP;
        for (int i = 0; i < nov; ++i) {
            int4 t = ovf[i];
            if (t.z != n) continue;
            ushort2 uu = *(const ushort2*)(el_bf + (size_t)t.y * HD + l2);
            float evx = bf2f(uu.x), evy = bf2f(uu.y);
            float x0 = evx + rv.x; x0 = fmaxf(x0, NEG * x0);
            float x1 = evy + rv.y; x1 = fmaxf(x1, NEG * x1);
            float p = x0 * a0 + x1 * a1;
            p += __shfl_xor(p, 1, 16);
            p += __shfl_xor(p, 2, 16);
            p += __shfl_xor(p, 4, 16);
            p += __shfl_xor(p, 8, 16);
            if ((lane & 15) == 0)
                out_a[(size_t)t.x * NH + hh] = __expf(p - m) * inv;
        }
    }
}

extern "C" void kernel_launch(void* const* d_in, const int* in_sizes, int n_in,
                              void* d_out, int out_size, void* d_ws, size_t ws_size,
                              hipStream_t stream) {
    const float* h    = (const float*)d_in[0];
    const int*   src  = (const int*)d_in[1];
    const int*   dst  = (const int*)d_in[2];
    const float* Wsrc = (const float*)d_in[3];
    const float* bsrc = (const float*)d_in[4];
    const float* Wdst = (const float*)d_in[5];
    const float* bdst = (const float*)d_in[6];
    const float* attn = (const float*)d_in[7];

    float* out_feat = (float*)d_out;                       // N*128 (er lives here too)
    float* out_a    = out_feat + (size_t)NNODES * HD;      // E*4

    // workspace layout (16B-aligned chunks), ~27 MB total
    ushort* Wt       = (ushort*)d_ws;                        // 256*256 bf16 (128 KB)
    ushort* el_bf    = Wt + 2 * HD * INDIM;                  // N*128 bf16 (12.8 MB)
    int*    cnt_work = (int*)(el_bf + (size_t)NNODES * HD);  // N (200 KB)
    int*    ovf_cnt  = cnt_work + NNODES;                    // 1 (+pad)
    int4*   ovf      = (int4*)(ovf_cnt + 4);                 // OVFCAP*16B (512 KB)
    int2*   bucket   = (int2*)(ovf + OVFCAP);                // N*BCAP*8B (12.8 MB)

    // fusedPre: clear cnt/ovf_cnt | W convert+transpose
    fusedPre_kernel<<<CLR_BLKS + CONVW_BLKS, 256, 0, stream>>>(cnt_work, Wsrc, Wdst, Wt);

    // fusedB: MFMA GEMM 128x256 (el -> ws, er -> d_out) | single-pass bucket scatter
    fusedB_kernel<<<GEMM_BLKS + SCAT_BLKS, 256, 0, stream>>>(
        h, Wt, bsrc, bdst, el_bf, out_feat, src, dst, cnt_work, bucket, ovf_cnt, ovf);

    node_fused_kernel<<<(NNODES + 3) / 4, 256, 0, stream>>>(
        el_bf, out_feat, cnt_work, bucket, ovf_cnt, ovf, attn, out_a);
}